// Round 13
// baseline (78.641 us; speedup 1.0000x reference)
//
#include <hip/hip_runtime.h>
#include <cstddef>
#include <cstdint>

#define NROWS  200000
#define CIN    32
#define COUT   64
#define KV     27
#define MW     8                       // m-tiles per wave (128 rows)
#define NTILES ((NROWS + 127) / 128)   // 1563 (last tile half-valid)

typedef __attribute__((ext_vector_type(8))) short  short8;
typedef __attribute__((ext_vector_type(4))) float  f32x4;

// RNE float -> bf16 (inputs finite)
__device__ __forceinline__ unsigned short f2bf(float x) {
  unsigned u = __builtin_bit_cast(unsigned, x);
  u += 0x7FFFu + ((u >> 16) & 1u);
  return (unsigned short)(u >> 16);
}

// Pack weight [27][32][64] f32 -> bf16 B-fragments, mfma_16x16x32 B layout:
// wsB[(k*4+t)*64 + lane][f] = W[k][(lane>>4)*8+f][t*16+(lane&15)]
__global__ void prep_weight_kernel(const float* __restrict__ w,
                                   short8* __restrict__ wsB) {
  int tid = blockIdx.x * blockDim.x + threadIdx.x;   // 27*4*64 = 6912
  if (tid >= KV * 4 * 64) return;
  int lane = tid & 63;
  int t    = (tid >> 6) & 3;
  int k    = tid >> 8;
  int col  = t * 16 + (lane & 15);
  int kin0 = (lane >> 4) * 8;
  short8 v;
#pragma unroll
  for (int f = 0; f < 8; ++f)
    v[f] = (short)f2bf(w[((size_t)k * CIN + kin0 + f) * COUT + col]);
  wsB[tid] = v;
}

// feats f32 [N][32] -> bf16 [N+1][32]; row N (pad) = zeros.
__global__ void prep_feats_kernel(const float* __restrict__ feats,
                                  short8* __restrict__ fb) {
  int i = blockIdx.x * blockDim.x + threadIdx.x;
  const int total8 = (NROWS + 1) * CIN / 8;          // 800004
  if (i >= total8) return;
  short8 v = {0, 0, 0, 0, 0, 0, 0, 0};
  if (i < NROWS * CIN / 8) {
    const f32x4* p = (const f32x4*)feats + (size_t)i * 2;
    f32x4 a = p[0], b = p[1];
#pragma unroll
    for (int f = 0; f < 4; ++f) {
      v[f]     = (short)f2bf(a[f]);
      v[4 + f] = (short)f2bf(b[f]);
    }
  }
  fb[i] = v;
}

// Main: champion mechanisms (idx-LDS, barrier-free, compiler-scheduled loop)
// at Mw=8 (128 rows/wave). Rationale: per-row cost model from R1/R2/R8 —
// the 4 KB/iter B-fragment delivery is ~half the per-iteration vector-memory
// return traffic and scales 1/Mw; Mw is the only lever that ever moved
// per-row time. Also: operand-swapped MFMA (bfr as A-operand) produces C^T
// fragments so each lane holds 4 CONSECUTIVE out columns -> dwordx4 stores
// (32 store instrs/tile instead of 128) and f32x4 bias init.
// 2-wave blocks keep the champion's 782-block dispatch shape.
__global__ __launch_bounds__(128, 2)
void spconv_mfma_kernel(const unsigned short* __restrict__ featsbf,
                        const short8* __restrict__ wsB,
                        const float* __restrict__ bias,
                        const int* __restrict__ in_idx,
                        float* __restrict__ out) {
  __shared__ int sIdx[2][KV][128];                   // 27,648 B

  const int tid  = threadIdx.x;
  const int lane = tid & 63;
  const int w    = tid >> 6;
  int wid = (int)blockIdx.x * 2 + w;                 // tile id
  if (wid >= NTILES) return;                         // barrier-free: ok
  const int row0 = wid << 7;                         // 128 rows per tile

  // ---- stage this wave's 27x128 idx block into LDS (per-wave region) ----
  // rows >= NROWS get the pad index N (zero row) so no guard in the k-loop.
  {
#pragma unroll
    for (int h = 0; h < 2; ++h) {
      const int r = h * 64 + lane;
      const int row = row0 + r;
      int tmp[KV];
#pragma unroll
      for (int k = 0; k < KV; ++k)
        tmp[k] = (row < NROWS) ? in_idx[(size_t)k * NROWS + row] : NROWS;
#pragma unroll
      for (int k = 0; k < KV; ++k)
        sIdx[w][k][r] = tmp[k];
    }
  }

  const int c16  = lane & 15;
  const int kg   = lane >> 4;
  const int koff = kg * 8;

  // acc[m][t][r] = C[row0 + m*16 + c16][t*16 + kg*4 + r]  (C^T fragment)
  f32x4 acc[MW][4];
#pragma unroll
  for (int t = 0; t < 4; ++t) {
    const f32x4 bv = *(const f32x4*)(bias + t * 16 + kg * 4);
#pragma unroll
    for (int m = 0; m < MW; ++m) acc[m][t] = bv;
  }

  const short8* bp = wsB + lane;

  // idx for k=0 (broadcast ds_read across kg groups)
  int idxc[MW], idxn[MW];
#pragma unroll
  for (int m = 0; m < MW; ++m) idxc[m] = sIdx[w][0][m * 16 + c16];

  for (int k = 0; k < KV; ++k) {
    const int kn = (k + 1 < KV) ? k + 1 : KV - 1;
#pragma unroll
    for (int m = 0; m < MW; ++m) idxn[m] = sIdx[w][kn][m * 16 + c16];

    short8 bfr[4];
#pragma unroll
    for (int t = 0; t < 4; ++t) bfr[t] = bp[(k * 4 + t) * 64];

    short8 afr[MW];
#pragma unroll
    for (int m = 0; m < MW; ++m)
      afr[m] = *(const short8*)(featsbf + (size_t)idxc[m] * CIN + koff);

    // swapped operands: D = bfr x afr = C^T tile (verified lane mapping:
    // D col = lane&15 = feat-row-within-16, D row = kg*4+r = out-col-within-16)
#pragma unroll
    for (int m = 0; m < MW; ++m) {
      acc[m][0] = __builtin_amdgcn_mfma_f32_16x16x32_bf16(bfr[0], afr[m], acc[m][0], 0, 0, 0);
      acc[m][1] = __builtin_amdgcn_mfma_f32_16x16x32_bf16(bfr[1], afr[m], acc[m][1], 0, 0, 0);
      acc[m][2] = __builtin_amdgcn_mfma_f32_16x16x32_bf16(bfr[2], afr[m], acc[m][2], 0, 0, 0);
      acc[m][3] = __builtin_amdgcn_mfma_f32_16x16x32_bf16(bfr[3], afr[m], acc[m][3], 0, 0, 0);
    }

#pragma unroll
    for (int m = 0; m < MW; ++m) idxc[m] = idxn[m];
  }

  // stores: one dwordx4 per (m,t); row guard only binds in the last tile
#pragma unroll
  for (int m = 0; m < MW; ++m) {
    const int row = row0 + m * 16 + c16;
    if (row < NROWS) {
      float* op = out + (size_t)row * COUT + kg * 4;
#pragma unroll
      for (int t = 0; t < 4; ++t)
        *(f32x4*)(op + t * 16) = acc[m][t];
    }
  }
}

// Correct-but-slow fallback if ws is tiny (shouldn't happen).
__global__ void spconv_naive_kernel(const float* __restrict__ feats,
                                    const float* __restrict__ w,
                                    const float* __restrict__ bias,
                                    const int* __restrict__ in_idx,
                                    float* __restrict__ out) {
  int gid = blockIdx.x * blockDim.x + threadIdx.x;
  if (gid >= NROWS * COUT) return;
  int row = gid / COUT, co = gid % COUT;
  float acc = bias[co];
  for (int k = 0; k < KV; ++k) {
    int idx = in_idx[(size_t)k * NROWS + row];
    if (idx < NROWS) {
      const float* fr = feats + (size_t)idx * CIN;
      const float* wk = w + (size_t)k * CIN * COUT + co;
#pragma unroll
      for (int c = 0; c < CIN; ++c) acc += fr[c] * wk[(size_t)c * COUT];
    }
  }
  out[gid] = acc;
}

extern "C" void kernel_launch(void* const* d_in, const int* in_sizes, int n_in,
                              void* d_out, int out_size, void* d_ws, size_t ws_size,
                              hipStream_t stream) {
  const float* feats  = (const float*)d_in[0];
  const float* weight = (const float*)d_in[1];
  const float* bias   = (const float*)d_in[2];
  const int*   in_idx = (const int*)d_in[3];
  float*       out    = (float*)d_out;

  const size_t wsB_bytes = (size_t)KV * 4 * 64 * 16;        // 110592
  const size_t fb_bytes  = (size_t)(NROWS + 1) * CIN * 2;   // 12800064
  short8*         wsB     = (short8*)d_ws;
  unsigned short* featsbf = (unsigned short*)((char*)d_ws + wsB_bytes);

  if (ws_size >= wsB_bytes + fb_bytes) {
    prep_weight_kernel<<<27, 256, 0, stream>>>(weight, wsB);
    prep_feats_kernel<<<((NROWS + 1) * CIN / 8 + 255) / 256, 256, 0, stream>>>(
        feats, (short8*)featsbf);
    const int blocks = (NTILES + 1) / 2;                     // 782
    spconv_mfma_kernel<<<blocks, 128, 0, stream>>>(
        featsbf, wsB, bias, in_idx, out);
  } else {
    spconv_naive_kernel<<<(NROWS * COUT + 255) / 256, 256, 0, stream>>>(
        feats, weight, bias, in_idx, out);
  }
}